// Round 5
// baseline (105.350 us; speedup 1.0000x reference)
//
#include <hip/hip_runtime.h>
#include <hip/hip_bf16.h>

// Fused: out[b,i,o] = sum_e w3[o,e] * sum_j adj[b,i,j] * leaky(sum_f ef[b,i,j,f]*w4[e,f])
// fp32 in/out; ef/w4 -> bf16 in-kernel, mfma_f32_16x16x32_bf16, fp32 acc.
//
// R5 change vs R4: ef staging via __builtin_amdgcn_global_load_lds (width=16).
// DMA loads consume no dest VGPRs -> all 8 tiles per wave are guaranteed in
// flight (8KB/wave, 128KB/CU at 4 blocks/CU), independent of register
// pressure. Consumption: manual s_waitcnt vmcnt(7-t) (m135 semantics) +
// ds_read_b128 from the wave-private LDS slice; no barriers in main loop.

typedef __attribute__((ext_vector_type(8))) short bf16x8;   // 8 bf16 = 4 VGPRs
typedef __attribute__((ext_vector_type(4))) float f32x4;
typedef __attribute__((ext_vector_type(4))) int   i32x4;

typedef __attribute__((address_space(1))) const unsigned int gu32;
typedef __attribute__((address_space(3))) unsigned int lu32;

constexpr int NN = 512;   // N
constexpr int NF = 16;    // edge features (K)
constexpr int NE = 64;    // embed dim
constexpr int WAVES = 4;
constexpr int JT = 16;                    // j per tile
constexpr int TPW = (NN / JT) / WAVES;    // 8 tiles per wave
constexpr int TILEF = JT * NF;            // 256 floats = 1KB per tile

__device__ __forceinline__ unsigned short f2bfu(float x) {
    return __builtin_bit_cast(unsigned short, __float2bfloat16(x));  // RNE
}
__device__ __forceinline__ int pack2(float lo, float hi) {
    return (int)((unsigned)f2bfu(lo) | ((unsigned)f2bfu(hi) << 16));
}

__global__ void __launch_bounds__(256, 4)
edge_embed_kernel(const float* __restrict__ ef,   // (B,N,N,16) fp32
                  const float* __restrict__ adj,  // (B,N,N)    fp32
                  const float* __restrict__ w4,   // (64,16)    fp32
                  const float* __restrict__ w3,   // (64,64)    fp32
                  float* __restrict__ out)        // (B,N,64)   fp32
{
    const int row  = blockIdx.x;          // b*N + i
    const int tid  = threadIdx.x;
    const int wave = tid >> 6;
    const int lane = tid & 63;
    const int m    = lane & 15;           // A-frag row / D col index
    const int quad = lane >> 4;           // D row group
    const int qb   = quad & 1;            // K half (quads 2,3 mirror 0,1; B pad rows are 0)

    __shared__ float adjf[NN];                      // per-wave 128-float slices
    __shared__ float stage[WAVES * TPW * TILEF];    // 32 KB ef staging
    __shared__ float partial[WAVES * NE];
    __shared__ float summed[NE];

    const int j0 = wave * (TPW * JT);
    const int sbase = wave * (TPW * TILEF);

    // ---- issue order == consumption order: adj, w4, then ef DMAs ----
    const float2 a2 = *(const float2*)(adj + (size_t)row * NN + j0 + 2 * lane);

    float4 wf[8];
    #pragma unroll
    for (int g = 0; g < 4; ++g) {
        wf[2 * g]     = make_float4(0.f, 0.f, 0.f, 0.f);
        wf[2 * g + 1] = make_float4(0.f, 0.f, 0.f, 0.f);
        if (quad < 2) {
            const float* p = w4 + ((g * 16 + m) * NF + qb * 8);
            wf[2 * g]     = *(const float4*)p;
            wf[2 * g + 1] = *(const float4*)(p + 4);
        }
    }

    // ef: 8 tile DMAs back-to-back, 1KB each (lane i -> lds_base + i*16B,
    // gptr lane i = tile_start + i*16B: LDS layout == global row-major).
    const float* efr = ef + (size_t)row * NN * NF;
    #pragma unroll
    for (int t = 0; t < TPW; ++t) {
        const float* gp = efr + (size_t)(j0 + t * JT) * NF + lane * 4;
        __builtin_amdgcn_global_load_lds((gu32*)gp, (lu32*)&stage[sbase + t * TILEF],
                                         16, 0, 0);
    }

    // ---- consume adj (per-wave LDS slice; wave-internal ordering) ----
    adjf[j0 + 2 * lane]     = a2.x;
    adjf[j0 + 2 * lane + 1] = a2.y;

    // ---- consume w4 -> B fragments (w4 is (E,F) = B^T layout) ----
    // lane holds w4[g*16+m][qb*8..+8); quads 2,3 = K-pad zeros (k=16..31).
    bf16x8 bfrag[4];
    #pragma unroll
    for (int g = 0; g < 4; ++g) {
        i32x4 v = {pack2(wf[2*g].x,   wf[2*g].y),
                   pack2(wf[2*g].z,   wf[2*g].w),
                   pack2(wf[2*g+1].x, wf[2*g+1].y),
                   pack2(wf[2*g+1].z, wf[2*g+1].w)};
        bfrag[g] = __builtin_bit_cast(bf16x8, v);
    }

    float accg[4] = {0.f, 0.f, 0.f, 0.f};  // per-lane: e = g*16 + m

    // ---- consume ef tiles FIFO; vmcnt(7-t) drains DMA t (DMAs were the
    // last 8 VMEM ops issued; w4/adj waits already executed above) ----
#define DO_TILE(T)                                                            \
    {                                                                         \
        __builtin_amdgcn_s_waitcnt(0x0F70 | (7 - (T)));  /* vmcnt only */     \
        const int sb = sbase + (T) * TILEF + m * 16 + qb * 8;                 \
        const float4 f0 = *(const float4*)&stage[sb];                         \
        const float4 f1 = *(const float4*)&stage[sb + 4];                     \
        i32x4 ai = {pack2(f0.x, f0.y), pack2(f0.z, f0.w),                     \
                    pack2(f1.x, f1.y), pack2(f1.z, f1.w)};                    \
        const bf16x8 a = __builtin_bit_cast(bf16x8, ai);                      \
        const float4 aj = *(const float4*)&adjf[j0 + (T) * JT + quad * 4];    \
        const float ajr[4] = {aj.x, aj.y, aj.z, aj.w};                        \
        const f32x4 zero = {0.f, 0.f, 0.f, 0.f};                              \
        _Pragma("unroll")                                                     \
        for (int g = 0; g < 4; ++g) {                                         \
            f32x4 d = __builtin_amdgcn_mfma_f32_16x16x32_bf16(a, bfrag[g],    \
                                                              zero, 0, 0, 0); \
            _Pragma("unroll")                                                 \
            for (int r = 0; r < 4; ++r) {                                     \
                float x = d[r];                                               \
                float v = fmaf(0.01f, fminf(x, 0.f), fmaxf(x, 0.f));          \
                accg[g] = fmaf(ajr[r], v, accg[g]);                           \
            }                                                                 \
        }                                                                     \
    }

    DO_TILE(0) DO_TILE(1) DO_TILE(2) DO_TILE(3)
    DO_TILE(4) DO_TILE(5) DO_TILE(6) DO_TILE(7)
#undef DO_TILE

    // ---- reduce over quads (lanes sharing m hold disjoint j-rows) ----
    #pragma unroll
    for (int g = 0; g < 4; ++g) {
        accg[g] += __shfl_xor(accg[g], 16);
        accg[g] += __shfl_xor(accg[g], 32);
    }
    if (quad == 0) {
        #pragma unroll
        for (int g = 0; g < 4; ++g)
            partial[wave * NE + g * 16 + m] = accg[g];
    }
    __syncthreads();

    // ---- cross-wave reduce (all threads reach both barriers) ----
    if (tid < NE)
        summed[tid] = partial[tid] + partial[NE + tid]
                    + partial[2 * NE + tid] + partial[3 * NE + tid];
    __syncthreads();

    // ---- w3 projection + store: wave 0 only, output o = lane ----
    if (wave == 0) {
        const float* w3r = w3 + lane * NE;   // w3 is (O,E) row-major
        float r = 0.f;
        #pragma unroll
        for (int e = 0; e < NE; e += 4) {
            float4 wv = *(const float4*)(w3r + e);
            float4 sv = *(const float4*)&summed[e];
            r = fmaf(wv.x, sv.x, r);
            r = fmaf(wv.y, sv.y, r);
            r = fmaf(wv.z, sv.z, r);
            r = fmaf(wv.w, sv.w, r);
        }
        out[(size_t)row * NE + lane] = r;
    }
}

extern "C" void kernel_launch(void* const* d_in, const int* in_sizes, int n_in,
                              void* d_out, int out_size, void* d_ws, size_t ws_size,
                              hipStream_t stream) {
    const float* ef  = (const float*)d_in[0];
    const float* adj = (const float*)d_in[1];
    const float* w4  = (const float*)d_in[2];
    const float* w3  = (const float*)d_in[3];
    float* out = (float*)d_out;

    const int rows = in_sizes[1] / NN;    // B*N = 2048
    edge_embed_kernel<<<dim3(rows), dim3(256), 0, stream>>>(ef, adj, w4, w3, out);
}

// Round 7
// 101.505 us; speedup vs baseline: 1.0379x; 1.0379x over previous
//
#include <hip/hip_runtime.h>
#include <hip/hip_bf16.h>

// Fused: out[b,i,o] = sum_e w3[o,e] * sum_j adj[b,i,j] * leaky(sum_f ef[b,i,j,f]*w4[e,f])
// fp32 in/out; ef/w4 -> bf16 in-kernel, mfma_f32_16x16x32_bf16, fp32 acc.
//
// R7 = R6 design (memory duty-cycle fix) with the waitcnt made a literal
// constant via macro expansion (builtin requires front-end constants).
// Each block handles TWO rows (grid 1024 = exactly 4 blocks/CU, one round)
// with a rolling 8-slot LDS ring per wave: consume tile t, issue DMA t+8
// into the freed slot. Row1's loads are in flight during row0's compute;
// epilogues deferred past the last tile (no barrier/vmcnt(0) drain hits
// in-flight DMAs). Steady state: 16 waves/CU x 8KB outstanding.

typedef __attribute__((ext_vector_type(8))) short bf16x8;   // 8 bf16 = 4 VGPRs
typedef __attribute__((ext_vector_type(4))) float f32x4;
typedef __attribute__((ext_vector_type(4))) int   i32x4;

typedef __attribute__((address_space(1))) const unsigned int gu32;
typedef __attribute__((address_space(3))) unsigned int lu32;

constexpr int NN = 512;   // N
constexpr int NF = 16;    // edge features (K)
constexpr int NE = 64;    // embed dim
constexpr int WAVES = 4;
constexpr int JT = 16;                    // j per tile
constexpr int TPW = (NN / JT) / WAVES;    // 8 tiles per wave per row
constexpr int TILEF = JT * NF;            // 256 floats = 1KB per tile

__device__ __forceinline__ unsigned short f2bfu(float x) {
    return __builtin_bit_cast(unsigned short, __float2bfloat16(x));  // RNE
}
__device__ __forceinline__ int pack2(float lo, float hi) {
    return (int)((unsigned)f2bfu(lo) | ((unsigned)f2bfu(hi) << 16));
}

__global__ void __launch_bounds__(256, 4)
edge_embed_kernel(const float* __restrict__ ef,   // (B,N,N,16) fp32
                  const float* __restrict__ adj,  // (B,N,N)    fp32
                  const float* __restrict__ w4,   // (64,16)    fp32
                  const float* __restrict__ w3,   // (64,64)    fp32
                  float* __restrict__ out)        // (B,N,64)   fp32
{
    const int row0 = blockIdx.x * 2;      // this block: rows row0, row0+1
    const int row1 = row0 + 1;
    const int tid  = threadIdx.x;
    const int wave = tid >> 6;
    const int lane = tid & 63;
    const int m    = lane & 15;           // A-frag row / D col index
    const int quad = lane >> 4;           // D row group
    const int qb   = quad & 1;            // K half (quads 2,3 mirror 0,1)

    __shared__ float stage[WAVES][TPW][TILEF];   // 32 KB ring (8 slots/wave)
    __shared__ float adjw[WAVES][2][128];        // 4 KB, per-wave adj slices
    __shared__ float partial[2][WAVES * NE];     // 2 KB
    __shared__ float summed[2][NE];              // 0.5 KB   -> 38.8 KB total

    const int j0 = wave * (TPW * JT);     // this wave's j range (both rows)

    // ---- issue order == consume order: adj0, adj1, w4, DMA row0 t0..7 ----
    const float2 a20 = *(const float2*)(adj + (size_t)row0 * NN + j0 + 2 * lane);
    const float2 a21 = *(const float2*)(adj + (size_t)row1 * NN + j0 + 2 * lane);

    float4 wf[8];
    #pragma unroll
    for (int g = 0; g < 4; ++g) {
        wf[2 * g]     = make_float4(0.f, 0.f, 0.f, 0.f);
        wf[2 * g + 1] = make_float4(0.f, 0.f, 0.f, 0.f);
        if (quad < 2) {
            const float* p = w4 + ((g * 16 + m) * NF + qb * 8);
            wf[2 * g]     = *(const float4*)p;
            wf[2 * g + 1] = *(const float4*)(p + 4);
        }
    }

    const float* efr0 = ef + (size_t)row0 * NN * NF;
    const float* efr1 = ef + (size_t)row1 * NN * NF;
    #pragma unroll
    for (int t = 0; t < TPW; ++t) {
        const float* gp = efr0 + (size_t)(j0 + t * JT) * NF + lane * 4;
        // LDS dest is wave-uniform base; HW scatters lane i -> base + i*16B,
        // which equals stage[wave][t][lane*4] (row-major tile) exactly.
        __builtin_amdgcn_global_load_lds((gu32*)gp, (lu32*)&stage[wave][t][0],
                                         16, 0, 0);
    }

    // ---- consume adj regs -> per-wave LDS (wave-internal, no barrier) ----
    *(float2*)&adjw[wave][0][2 * lane] = a20;
    *(float2*)&adjw[wave][1][2 * lane] = a21;

    // ---- consume w4 -> B fragments (w4 is (E,F) = B^T layout) ----
    // lane holds w4[g*16+m][qb*8..+8); quads 2,3 stay zero = K-pad k=16..31.
    bf16x8 bfrag[4];
    #pragma unroll
    for (int g = 0; g < 4; ++g) {
        i32x4 v = {pack2(wf[2*g].x,   wf[2*g].y),
                   pack2(wf[2*g].z,   wf[2*g].w),
                   pack2(wf[2*g+1].x, wf[2*g+1].y),
                   pack2(wf[2*g+1].z, wf[2*g+1].w)};
        bfrag[g] = __builtin_bit_cast(bf16x8, v);
    }

    float accg[2][4] = {{0.f,0.f,0.f,0.f},{0.f,0.f,0.f,0.f}};

    // ---- 16 tiles (row0: T=0..7, row1: T=8..15), 8-slot rolling ring ----
    // Before consuming tile T: issued = 8 + min(T,8) DMAs, need 0..T done
    // -> vmcnt(7) for T<8, else vmcnt(15-T). DMAs are the newest VMEM ops,
    // so the wait is exact for them (older loads already waited on above).
#define DO_TILE(T)                                                            \
    {                                                                         \
        __builtin_amdgcn_s_waitcnt(0x0F70 | ((T) < 8 ? 7 : 15 - (T)));        \
        const int r  = (T) >> 3;          /* which row */                     \
        const int lt = (T) & 7;           /* ring slot / local tile */        \
        const float* sb = &stage[wave][lt][m * 16 + qb * 8];                  \
        const float4 f0 = *(const float4*)sb;                                 \
        const float4 f1 = *(const float4*)(sb + 4);                           \
        i32x4 ai = {pack2(f0.x, f0.y), pack2(f0.z, f0.w),                     \
                    pack2(f1.x, f1.y), pack2(f1.z, f1.w)};                    \
        const bf16x8 a = __builtin_bit_cast(bf16x8, ai);                      \
        const float4 aj = *(const float4*)&adjw[wave][r][lt * JT + quad * 4]; \
        const float ajr[4] = {aj.x, aj.y, aj.z, aj.w};                        \
        const f32x4 zero = {0.f, 0.f, 0.f, 0.f};                              \
        _Pragma("unroll")                                                     \
        for (int g = 0; g < 4; ++g) {                                         \
            f32x4 d = __builtin_amdgcn_mfma_f32_16x16x32_bf16(a, bfrag[g],    \
                                                              zero, 0, 0, 0); \
            _Pragma("unroll")                                                 \
            for (int rr = 0; rr < 4; ++rr) {                                  \
                float x = d[rr];                                              \
                float v = fmaxf(x, 0.01f * x);        /* LeakyReLU */         \
                accg[r][g] = fmaf(ajr[rr], v, accg[r][g]);                    \
            }                                                                 \
        }                                                                     \
        if ((T) < TPW) {  /* refill drained slot with row1 tile lt */         \
            const float* gp = efr1 + (size_t)(j0 + lt * JT) * NF + lane * 4;  \
            __builtin_amdgcn_global_load_lds((gu32*)gp,                       \
                                             (lu32*)&stage[wave][lt][0],      \
                                             16, 0, 0);                       \
        }                                                                     \
    }

    DO_TILE(0)  DO_TILE(1)  DO_TILE(2)  DO_TILE(3)
    DO_TILE(4)  DO_TILE(5)  DO_TILE(6)  DO_TILE(7)
    DO_TILE(8)  DO_TILE(9)  DO_TILE(10) DO_TILE(11)
    DO_TILE(12) DO_TILE(13) DO_TILE(14) DO_TILE(15)
#undef DO_TILE

    // ---- epilogues for BOTH rows (nothing left in flight; barriers safe) ----
    #pragma unroll
    for (int r = 0; r < 2; ++r)
        #pragma unroll
        for (int g = 0; g < 4; ++g) {
            accg[r][g] += __shfl_xor(accg[r][g], 16);
            accg[r][g] += __shfl_xor(accg[r][g], 32);
        }
    if (quad == 0) {
        #pragma unroll
        for (int r = 0; r < 2; ++r)
            #pragma unroll
            for (int g = 0; g < 4; ++g)
                partial[r][wave * NE + g * 16 + m] = accg[r][g];
    }
    __syncthreads();

    if (tid < 2 * NE) {
        const int r = tid >> 6, e = tid & 63;
        summed[r][e] = partial[r][e] + partial[r][NE + e]
                     + partial[r][2 * NE + e] + partial[r][3 * NE + e];
    }
    __syncthreads();

    // ---- w3 projection + store: wave 0, output o = lane, both rows ----
    if (wave == 0) {
        const float* w3r = w3 + lane * NE;   // w3 is (O,E) row-major
        float r0 = 0.f, r1 = 0.f;
        #pragma unroll
        for (int e = 0; e < NE; e += 4) {
            float4 wv = *(const float4*)(w3r + e);
            float4 s0 = *(const float4*)&summed[0][e];
            float4 s1 = *(const float4*)&summed[1][e];
            r0 = fmaf(wv.x, s0.x, fmaf(wv.y, s0.y, fmaf(wv.z, s0.z, fmaf(wv.w, s0.w, r0))));
            r1 = fmaf(wv.x, s1.x, fmaf(wv.y, s1.y, fmaf(wv.z, s1.z, fmaf(wv.w, s1.w, r1))));
        }
        out[(size_t)row0 * NE + lane] = r0;
        out[(size_t)row1 * NE + lane] = r1;
    }
}

extern "C" void kernel_launch(void* const* d_in, const int* in_sizes, int n_in,
                              void* d_out, int out_size, void* d_ws, size_t ws_size,
                              hipStream_t stream) {
    const float* ef  = (const float*)d_in[0];
    const float* adj = (const float*)d_in[1];
    const float* w4  = (const float*)d_in[2];
    const float* w3  = (const float*)d_in[3];
    float* out = (float*)d_out;

    const int rows = in_sizes[1] / NN;    // B*N = 2048
    edge_embed_kernel<<<dim3(rows / 2), dim3(256), 0, stream>>>(ef, adj, w4, w3, out);
}